// Round 8
// baseline (196.583 us; speedup 1.0000x reference)
//
#include <hip/hip_runtime.h>
#include <math.h>

#define BSZ 2
#define LSEQ 4096
#define DM 256      // d_model
#define DI 256      // d_inner
#define DS 16       // d_state
#define DR 16       // dt_rank
#define NIN 512     // 2*DI
#define NCHUNK 256
#define LCHUNK 16
#define NB2 320     // padded Bcat width (288 real: 256 dt + 32 bc)

typedef __attribute__((ext_vector_type(8))) short short8;
typedef __attribute__((ext_vector_type(4))) float floatx4;

__device__ __forceinline__ float sigmoid_f(float v) {
    return __builtin_amdgcn_rcpf(1.0f + __expf(-v));
}

__device__ __forceinline__ unsigned int bf16_rne(float v) {
    unsigned int u = __float_as_uint(v);
    return (u + 0x7FFFu + ((u >> 16) & 1u)) >> 16;
}

// ---------------- setup: split W_in/W_out transposed + build BcatT (fused wsplit+bcat) ----------------
__global__ __launch_bounds__(512) void setup_k(const float* __restrict__ W_in,
                                               const float* __restrict__ W_out,
                                               const float* __restrict__ W_x,
                                               const float* __restrict__ W_dt,
                                               unsigned short* __restrict__ WinT_hi,
                                               unsigned short* __restrict__ WinT_lo,
                                               unsigned short* __restrict__ WoutT_hi,
                                               unsigned short* __restrict__ WoutT_lo,
                                               unsigned short* __restrict__ BcatT_hi,
                                               unsigned short* __restrict__ BcatT_lo) {
    __shared__ float wr[16];
    const int k = blockIdx.x;          // 0..255
    const int t = threadIdx.x;         // 0..511
    if (t < 16) wr[t] = W_x[(size_t)k * 48 + t];
    {
        float v = W_in[(size_t)k * NIN + t];
        unsigned int h = bf16_rne(v);
        float r = v - __uint_as_float(h << 16);
        WinT_hi[(size_t)t * DM + k] = (unsigned short)h;
        WinT_lo[(size_t)t * DM + k] = (unsigned short)bf16_rne(r);
    }
    if (t < DM) {
        float v = W_out[(size_t)k * DM + t];
        unsigned int h = bf16_rne(v);
        float r = v - __uint_as_float(h << 16);
        WoutT_hi[(size_t)t * DM + k] = (unsigned short)h;
        WoutT_lo[(size_t)t * DM + k] = (unsigned short)bf16_rne(r);
    }
    __syncthreads();
    if (t < NB2) {
        float v;
        if (t < 256) {
            float acc = 0.f;
#pragma unroll
            for (int r = 0; r < 16; ++r) acc = fmaf(wr[r], W_dt[r * DI + t], acc);
            v = acc;
        } else if (t < 288) {
            v = W_x[(size_t)k * 48 + 16 + (t - 256)];
        } else {
            v = 0.f;
        }
        unsigned int h = bf16_rne(v);
        float r = v - __uint_as_float(h << 16);
        BcatT_hi[(size_t)t * DM + k] = (unsigned short)h;
        BcatT_lo[(size_t)t * DM + k] = (unsigned short)bf16_rne(r);
    }
}

// ---------------- gemm_in (MFMA bf16x3): xz = x^T @ W_in; z-half gets SiLU in epilogue ----------------
__global__ __launch_bounds__(256) void gemm_in_k(const float* __restrict__ x,
                                                 const unsigned short* __restrict__ WT_hi,
                                                 const unsigned short* __restrict__ WT_lo,
                                                 float* __restrict__ xz) {
    __shared__ unsigned short sA[128][40];
    __shared__ unsigned short sB[128][40];
    const int b  = blockIdx.z;
    const int m0 = blockIdx.y * 64;
    const int n0 = blockIdx.x * 64;
    const int t  = threadIdx.x;
    const int w    = t >> 6;
    const int lane = t & 63;
    const int kp = t & 15;
    const int g  = t >> 4;

    const int mwb = (w & 1) * 32;
    const int nwb = (w >> 1) * 32;
    const int fr  = lane & 15;
    const int q   = lane >> 4;

    const int brow = t >> 2;
    const int bkq8 = (t & 3) * 8;

    floatx4 acc[2][2];
#pragma unroll
    for (int mi = 0; mi < 2; ++mi)
#pragma unroll
        for (int ni = 0; ni < 2; ++ni) acc[mi][ni] = (floatx4){0.f, 0.f, 0.f, 0.f};

    for (int k0 = 0; k0 < DM; k0 += 32) {
        {
            const float* pa = x + ((size_t)b * DM + k0 + 2 * kp) * LSEQ + m0 + 4 * g;
            float4 fa0 = *(const float4*)(pa);
            float4 fa1 = *(const float4*)(pa + LSEQ);
            const float* a0 = (const float*)&fa0;
            const float* a1 = (const float*)&fa1;
#pragma unroll
            for (int j = 0; j < 4; ++j) {
                int m = 4 * g + j;
                unsigned int h0 = bf16_rne(a0[j]);
                unsigned int h1 = bf16_rne(a1[j]);
                float r0 = a0[j] - __uint_as_float(h0 << 16);
                float r1 = a1[j] - __uint_as_float(h1 << 16);
                unsigned int l0 = bf16_rne(r0);
                unsigned int l1 = bf16_rne(r1);
                *(unsigned int*)&sA[m][2 * kp]      = h0 | (h1 << 16);
                *(unsigned int*)&sA[64 + m][2 * kp] = l0 | (l1 << 16);
            }
            const size_t boff = (size_t)(n0 + brow) * DM + k0 + bkq8;
            *(short8*)&sB[brow][bkq8]      = *(const short8*)(WT_hi + boff);
            *(short8*)&sB[64 + brow][bkq8] = *(const short8*)(WT_lo + boff);
        }
        __syncthreads();

        short8 ah[2], al[2], bh[2], bl[2];
#pragma unroll
        for (int mi = 0; mi < 2; ++mi) {
            int mr = mwb + mi * 16 + fr;
            ah[mi] = *(const short8*)&sA[mr][q * 8];
            al[mi] = *(const short8*)&sA[64 + mr][q * 8];
        }
#pragma unroll
        for (int ni = 0; ni < 2; ++ni) {
            int nr = nwb + ni * 16 + fr;
            bh[ni] = *(const short8*)&sB[nr][q * 8];
            bl[ni] = *(const short8*)&sB[64 + nr][q * 8];
        }
#pragma unroll
        for (int mi = 0; mi < 2; ++mi)
#pragma unroll
            for (int ni = 0; ni < 2; ++ni) {
                acc[mi][ni] = __builtin_amdgcn_mfma_f32_16x16x32_bf16(ah[mi], bh[ni], acc[mi][ni], 0, 0, 0);
                acc[mi][ni] = __builtin_amdgcn_mfma_f32_16x16x32_bf16(ah[mi], bl[ni], acc[mi][ni], 0, 0, 0);
                acc[mi][ni] = __builtin_amdgcn_mfma_f32_16x16x32_bf16(al[mi], bh[ni], acc[mi][ni], 0, 0, 0);
            }
        __syncthreads();
    }

    const bool isz = (n0 >= 256);   // z-half: store silu(z)
#pragma unroll
    for (int mi = 0; mi < 2; ++mi)
#pragma unroll
        for (int ni = 0; ni < 2; ++ni) {
#pragma unroll
            for (int r = 0; r < 4; ++r) {
                int m = m0 + mwb + mi * 16 + q * 4 + r;
                int n = n0 + nwb + ni * 16 + fr;
                float v = acc[mi][ni][r];
                if (isz) v = v * sigmoid_f(v);
                xz[((size_t)b * LSEQ + m) * NIN + n] = v;
            }
        }
}

// ---------------- gemm_x2c (MFMA bf16x3, conv+SiLU fused into A-staging) ----------------
// [dt | bc] = silu(conv(xz_x)) @ Bcat ; also writes xc (from n-tile 0 blocks only)
__global__ __launch_bounds__(256) void gemm_x2c_k(const float* __restrict__ xz,
                                                  const float* __restrict__ conv_w,
                                                  const float* __restrict__ conv_b,
                                                  const unsigned short* __restrict__ BT_hi,
                                                  const unsigned short* __restrict__ BT_lo,
                                                  const float* __restrict__ b_dt,
                                                  float* __restrict__ xc,
                                                  float* __restrict__ dt,
                                                  float* __restrict__ bc) {
    __shared__ unsigned short sA[128][40];
    __shared__ unsigned short sB[128][40];
    const int m0 = blockIdx.y * 64;
    const int n0 = blockIdx.x * 64;
    const int t  = threadIdx.x;
    const int w    = t >> 6;
    const int lane = t & 63;
    const int mwb = (w & 1) * 32;
    const int nwb = (w >> 1) * 32;
    const int fr  = lane & 15;
    const int q   = lane >> 4;

    const int row = t >> 2;          // m-rel 0..63
    const int kq8 = (t & 3) * 8;     // d-chunk base within k0

    const int m  = m0 + row;
    const int bb = m >> 12;
    const int l  = m & (LSEQ - 1);
    const bool write_xc = (blockIdx.x == 0);

    floatx4 acc[2][2];
#pragma unroll
    for (int mi = 0; mi < 2; ++mi)
#pragma unroll
        for (int ni = 0; ni < 2; ++ni) acc[mi][ni] = (floatx4){0.f, 0.f, 0.f, 0.f};

    for (int k0 = 0; k0 < DI; k0 += 32) {
        {
            const int d0 = k0 + kq8;   // 8 consecutive d
            float v[8];
            *(float4*)(v)     = *(const float4*)(conv_b + d0);
            *(float4*)(v + 4) = *(const float4*)(conv_b + d0 + 4);
            float cw[32];
#pragma unroll
            for (int j4 = 0; j4 < 8; ++j4)
                *(float4*)(cw + j4 * 4) = *(const float4*)(conv_w + (d0 + j4) * 4);
#pragma unroll
            for (int j = 0; j < 4; ++j) {
                int ls = l - 3 + j;
                if (ls >= 0) {
                    float xv[8];
                    const float* pz = xz + ((size_t)bb * LSEQ + ls) * NIN + d0;
                    *(float4*)(xv)     = *(const float4*)(pz);
                    *(float4*)(xv + 4) = *(const float4*)(pz + 4);
#pragma unroll
                    for (int e = 0; e < 8; ++e)
                        v[e] = fmaf(xv[e], cw[e * 4 + j], v[e]);
                }
            }
            short8 hi, lo;
#pragma unroll
            for (int e = 0; e < 8; ++e) {
                float xcv = v[e] * sigmoid_f(v[e]);
                v[e] = xcv;
                unsigned int h = bf16_rne(xcv);
                float r = xcv - __uint_as_float(h << 16);
                hi[e] = (short)h;
                lo[e] = (short)bf16_rne(r);
            }
            if (write_xc) {
                float* pxc = xc + (size_t)m * DI + d0;
                *(float4*)(pxc)     = *(float4*)(v);
                *(float4*)(pxc + 4) = *(float4*)(v + 4);
            }
            *(short8*)&sA[row][kq8]      = hi;
            *(short8*)&sA[64 + row][kq8] = lo;

            const size_t boff = (size_t)(n0 + row) * DM + k0 + kq8;
            *(short8*)&sB[row][kq8]      = *(const short8*)(BT_hi + boff);
            *(short8*)&sB[64 + row][kq8] = *(const short8*)(BT_lo + boff);
        }
        __syncthreads();

        short8 ah[2], al[2], bh[2], bl[2];
#pragma unroll
        for (int mi = 0; mi < 2; ++mi) {
            int mr = mwb + mi * 16 + fr;
            ah[mi] = *(const short8*)&sA[mr][q * 8];
            al[mi] = *(const short8*)&sA[64 + mr][q * 8];
        }
#pragma unroll
        for (int ni = 0; ni < 2; ++ni) {
            int nr = nwb + ni * 16 + fr;
            bh[ni] = *(const short8*)&sB[nr][q * 8];
            bl[ni] = *(const short8*)&sB[64 + nr][q * 8];
        }
#pragma unroll
        for (int mi = 0; mi < 2; ++mi)
#pragma unroll
            for (int ni = 0; ni < 2; ++ni) {
                acc[mi][ni] = __builtin_amdgcn_mfma_f32_16x16x32_bf16(ah[mi], bh[ni], acc[mi][ni], 0, 0, 0);
                acc[mi][ni] = __builtin_amdgcn_mfma_f32_16x16x32_bf16(ah[mi], bl[ni], acc[mi][ni], 0, 0, 0);
                acc[mi][ni] = __builtin_amdgcn_mfma_f32_16x16x32_bf16(al[mi], bh[ni], acc[mi][ni], 0, 0, 0);
            }
        __syncthreads();
    }

#pragma unroll
    for (int mi = 0; mi < 2; ++mi)
#pragma unroll
        for (int ni = 0; ni < 2; ++ni) {
            int n = n0 + nwb + ni * 16 + fr;
            if (n < 256) {
                float bd = b_dt[n];
#pragma unroll
                for (int r = 0; r < 4; ++r) {
                    int mm = m0 + mwb + mi * 16 + q * 4 + r;
                    float a2 = acc[mi][ni][r] + bd;
                    float sp = fmaxf(a2, 0.f) + __logf(1.f + __expf(-fabsf(a2)));
                    dt[(size_t)mm * DI + n] = sp;
                }
            } else if (n < 288) {
#pragma unroll
                for (int r = 0; r < 4; ++r) {
                    int mm = m0 + mwb + mi * 16 + q * 4 + r;
                    bc[(size_t)mm * 32 + (n - 256)] = acc[mi][ni][r];
                }
            }
        }
}

// ---------------- scan phase A: local final F + per-chunk dt-sum ----------------
__global__ __launch_bounds__(256) void scan_a_k(const float* __restrict__ dt,
                                                const float* __restrict__ xc,
                                                const float* __restrict__ bc,
                                                const float* __restrict__ A_log,
                                                float* __restrict__ sumdt,
                                                float* __restrict__ Fst) {
    __shared__ float Bl[LCHUNK][16];
    const int blk   = blockIdx.x;
    const int b     = blk / NCHUNK;
    const int chunk = blk % NCHUNK;
    const int d     = threadIdx.x;
    const int l0    = chunk * LCHUNK;

    if (d < LCHUNK * 4) {
        int l = d >> 2, q = d & 3;
        *(float4*)(&Bl[l][q * 4]) =
            *(const float4*)(bc + (size_t)(b * LSEQ + l0 + l) * 32 + q * 4);
    }
    float Ads[16];
#pragma unroll
    for (int s = 0; s < 16; ++s) Ads[s] = -expf(A_log[d * DS + s]);
    __syncthreads();

    float h[16];
#pragma unroll
    for (int s = 0; s < 16; ++s) h[s] = 0.f;
    float sd = 0.f;

    const float* dtp = dt + ((size_t)b * LSEQ + l0) * DI + d;
    const float* xcp = xc + ((size_t)b * LSEQ + l0) * DI + d;

#pragma unroll 4
    for (int i = 0; i < LCHUNK; ++i) {
        float dtv = dtp[(size_t)i * DI];
        float xcv = xcp[(size_t)i * DI];
        float du  = dtv * xcv;
        sd += dtv;
        float4 b0 = *(float4*)(&Bl[i][0]);
        float4 b1 = *(float4*)(&Bl[i][4]);
        float4 b2 = *(float4*)(&Bl[i][8]);
        float4 b3 = *(float4*)(&Bl[i][12]);
        float bv[16] = {b0.x,b0.y,b0.z,b0.w, b1.x,b1.y,b1.z,b1.w,
                        b2.x,b2.y,b2.z,b2.w, b3.x,b3.y,b3.z,b3.w};
#pragma unroll
        for (int s = 0; s < 16; ++s) {
            float a = __expf(dtv * Ads[s]);
            h[s] = fmaf(h[s], a, du * bv[s]);
        }
    }
    size_t base = ((size_t)(b * DI + d) * NCHUNK + chunk) * DS;
#pragma unroll
    for (int q = 0; q < 4; ++q)
        *(float4*)(Fst + base + q * 4) = make_float4(h[q*4], h[q*4+1], h[q*4+2], h[q*4+3]);
    sumdt[(size_t)(b * DI + d) * NCHUNK + chunk] = sd;
}

// ---------------- scan phase B: chunk-prefix; P reconstructed from sumdt ----------------
__global__ __launch_bounds__(256) void scan_b_k(const float* __restrict__ sumdt,
                                                const float* __restrict__ A_log,
                                                float* __restrict__ Fst) {
    const int t = blockIdx.x * 256 + threadIdx.x;
    const int s = t & 15;
    const int d = (t >> 4) & (DI - 1);
    const int b = t >> 12;
    const float Ads = -expf(A_log[d * DS + s]);
    size_t base = ((size_t)(b * DI + d) * NCHUNK) * DS + s;
    const float* sdp = sumdt + (size_t)(b * DI + d) * NCHUNK;
    float st = 0.f;
#pragma unroll 8
    for (int c = 0; c < NCHUNK; ++c) {
        size_t idx = base + (size_t)c * DS;
        float P = __expf(sdp[c] * Ads);
        float F = Fst[idx];
        Fst[idx] = st;
        st = fmaf(P, st, F);
    }
}

// ---------------- scan phase C ----------------
__global__ __launch_bounds__(256) void scan_c_k(const float* __restrict__ dt,
                                                const float* __restrict__ xc,
                                                const float* __restrict__ bc,
                                                const float* __restrict__ xz,
                                                const float* __restrict__ A_log,
                                                const float* __restrict__ Dw,
                                                const float* __restrict__ carry,
                                                float* __restrict__ y) {
    __shared__ float BC[LCHUNK][32];
    const int blk   = blockIdx.x;
    const int b     = blk / NCHUNK;
    const int chunk = blk % NCHUNK;
    const int d     = threadIdx.x;
    const int l0    = chunk * LCHUNK;

    if (d < LCHUNK * 8) {
        int l = d >> 3, q = d & 7;
        *(float4*)(&BC[l][q * 4]) =
            *(const float4*)(bc + (size_t)(b * LSEQ + l0 + l) * 32 + q * 4);
    }
    float Ads[16];
#pragma unroll
    for (int s = 0; s < 16; ++s) Ads[s] = -expf(A_log[d * DS + s]);
    const float Dd = Dw[d];

    float h[16];
    size_t cbase = ((size_t)(b * DI + d) * NCHUNK + chunk) * DS;
#pragma unroll
    for (int q = 0; q < 4; ++q) {
        float4 c4 = *(const float4*)(carry + cbase + q * 4);
        h[q*4] = c4.x; h[q*4+1] = c4.y; h[q*4+2] = c4.z; h[q*4+3] = c4.w;
    }
    __syncthreads();

    const float* dtp = dt + ((size_t)b * LSEQ + l0) * DI + d;
    const float* xcp = xc + ((size_t)b * LSEQ + l0) * DI + d;
    const float* zp  = xz + ((size_t)b * LSEQ + l0) * NIN + DI + d;   // already silu'd
    float* yout      = y  + ((size_t)b * LSEQ + l0) * DI + d;

#pragma unroll 4
    for (int i = 0; i < LCHUNK; ++i) {
        float dtv = dtp[(size_t)i * DI];
        float xcv = xcp[(size_t)i * DI];
        float zs  = zp[(size_t)i * NIN];
        float du  = dtv * xcv;
        float4 b0 = *(float4*)(&BC[i][0]);
        float4 b1 = *(float4*)(&BC[i][4]);
        float4 b2 = *(float4*)(&BC[i][8]);
        float4 b3 = *(float4*)(&BC[i][12]);
        float4 c0 = *(float4*)(&BC[i][16]);
        float4 c1 = *(float4*)(&BC[i][20]);
        float4 c2 = *(float4*)(&BC[i][24]);
        float4 c3 = *(float4*)(&BC[i][28]);
        float bv[16] = {b0.x,b0.y,b0.z,b0.w, b1.x,b1.y,b1.z,b1.w,
                        b2.x,b2.y,b2.z,b2.w, b3.x,b3.y,b3.z,b3.w};
        float cv[16] = {c0.x,c0.y,c0.z,c0.w, c1.x,c1.y,c1.z,c1.w,
                        c2.x,c2.y,c2.z,c2.w, c3.x,c3.y,c3.z,c3.w};
        float yv = 0.f;
#pragma unroll
        for (int s = 0; s < 16; ++s) {
            float a = __expf(dtv * Ads[s]);
            h[s] = fmaf(h[s], a, du * bv[s]);
            yv = fmaf(h[s], cv[s], yv);
        }
        float yf = fmaf(xcv, Dd, yv);
        yout[(size_t)i * DI] = yf * zs;
    }
}

// ---------------- gemm_out (MFMA bf16x3): out[b,c,l] = sum_d y[b,l,d] * W_out[d,c] ----------------
__global__ __launch_bounds__(256) void gemm_out_k(const float* __restrict__ y,
                                                  const unsigned short* __restrict__ WT_hi,
                                                  const unsigned short* __restrict__ WT_lo,
                                                  float* __restrict__ out) {
    __shared__ unsigned short sA[128][40];
    __shared__ unsigned short sB[128][40];
    const int b  = blockIdx.z;
    const int m0 = blockIdx.y * 64;    // l
    const int n0 = blockIdx.x * 64;    // c
    const int t  = threadIdx.x;
    const int w    = t >> 6;
    const int lane = t & 63;
    const int mwb = (w & 1) * 32;
    const int nwb = (w >> 1) * 32;
    const int fr  = lane & 15;
    const int q   = lane >> 4;

    const int row = t >> 2;
    const int kq8 = (t & 3) * 8;

    floatx4 acc[2][2];
#pragma unroll
    for (int mi = 0; mi < 2; ++mi)
#pragma unroll
        for (int ni = 0; ni < 2; ++ni) acc[mi][ni] = (floatx4){0.f, 0.f, 0.f, 0.f};

    for (int k0 = 0; k0 < DI; k0 += 32) {
        {
            const float* pa = y + ((size_t)b * LSEQ + m0 + row) * DI + k0 + kq8;
            float v[8];
            *(float4*)(v)     = *(const float4*)(pa);
            *(float4*)(v + 4) = *(const float4*)(pa + 4);
            short8 hi, lo;
#pragma unroll
            for (int j = 0; j < 8; ++j) {
                unsigned int h = bf16_rne(v[j]);
                float r = v[j] - __uint_as_float(h << 16);
                hi[j] = (short)h;
                lo[j] = (short)bf16_rne(r);
            }
            *(short8*)&sA[row][kq8]      = hi;
            *(short8*)&sA[64 + row][kq8] = lo;

            const size_t boff = (size_t)(n0 + row) * DM + k0 + kq8;
            *(short8*)&sB[row][kq8]      = *(const short8*)(WT_hi + boff);
            *(short8*)&sB[64 + row][kq8] = *(const short8*)(WT_lo + boff);
        }
        __syncthreads();

        short8 ah[2], al[2], bh[2], bl[2];
#pragma unroll
        for (int mi = 0; mi < 2; ++mi) {
            int mr = mwb + mi * 16 + fr;
            ah[mi] = *(const short8*)&sA[mr][q * 8];
            al[mi] = *(const short8*)&sA[64 + mr][q * 8];
        }
#pragma unroll
        for (int ni = 0; ni < 2; ++ni) {
            int nr = nwb + ni * 16 + fr;
            bh[ni] = *(const short8*)&sB[nr][q * 8];
            bl[ni] = *(const short8*)&sB[64 + nr][q * 8];
        }
#pragma unroll
        for (int mi = 0; mi < 2; ++mi)
#pragma unroll
            for (int ni = 0; ni < 2; ++ni) {
                acc[mi][ni] = __builtin_amdgcn_mfma_f32_16x16x32_bf16(ah[mi], bh[ni], acc[mi][ni], 0, 0, 0);
                acc[mi][ni] = __builtin_amdgcn_mfma_f32_16x16x32_bf16(ah[mi], bl[ni], acc[mi][ni], 0, 0, 0);
                acc[mi][ni] = __builtin_amdgcn_mfma_f32_16x16x32_bf16(al[mi], bh[ni], acc[mi][ni], 0, 0, 0);
            }
        __syncthreads();
    }

#pragma unroll
    for (int mi = 0; mi < 2; ++mi)
#pragma unroll
        for (int ni = 0; ni < 2; ++ni) {
            int c = n0 + nwb + ni * 16 + fr;
            float* op = out + ((size_t)b * DM + c) * LSEQ + m0 + mwb + mi * 16 + q * 4;
            *(float4*)op = make_float4(acc[mi][ni][0], acc[mi][ni][1],
                                       acc[mi][ni][2], acc[mi][ni][3]);
        }
}

extern "C" void kernel_launch(void* const* d_in, const int* in_sizes, int n_in,
                              void* d_out, int out_size, void* d_ws, size_t ws_size,
                              hipStream_t stream) {
    const float* x      = (const float*)d_in[0];
    const float* W_in   = (const float*)d_in[1];
    const float* conv_w = (const float*)d_in[2];
    const float* conv_b = (const float*)d_in[3];
    const float* W_x    = (const float*)d_in[4];
    const float* W_dt   = (const float*)d_in[5];
    const float* b_dt   = (const float*)d_in[6];
    const float* A_log  = (const float*)d_in[7];
    const float* Dw     = (const float*)d_in[8];
    const float* W_out  = (const float*)d_in[9];
    float* out = (float*)d_out;

    float* ws    = (float*)d_ws;
    float* xz    = ws;                    // B*L*512            = 4,194,304
    float* xc    = xz + 4194304;          // B*L*256            = 2,097,152
    float* bc    = xc + 2097152;          // B*L*32             =   262,144
    float* dtb   = bc + 262144;           // B*L*256            = 2,097,152
    float* sumdt = dtb + 2097152;         // B*DI*NCHUNK        =   131,072
    float* Fst   = sumdt + 131072;        // B*DI*NCHUNK*DS     = 2,097,152
    float* yb    = Fst + 2097152;         // B*L*DI             = 2,097,152
    unsigned short* WinT_hi  = (unsigned short*)(yb + 2097152);   // 512*256
    unsigned short* WinT_lo  = WinT_hi + 131072;
    unsigned short* WoutT_hi = WinT_lo + 131072;                  // 256*256
    unsigned short* WoutT_lo = WoutT_hi + 65536;
    unsigned short* BcatT_hi = WoutT_lo + 65536;                  // 320*256
    unsigned short* BcatT_lo = BcatT_hi + 81920;

    setup_k    <<<dim3(256), 512, 0, stream>>>(W_in, W_out, W_x, W_dt,
                                               WinT_hi, WinT_lo, WoutT_hi, WoutT_lo,
                                               BcatT_hi, BcatT_lo);
    gemm_in_k  <<<dim3(8, 64, BSZ), 256, 0, stream>>>(x, WinT_hi, WinT_lo, xz);
    gemm_x2c_k <<<dim3(5, 128), 256, 0, stream>>>(xz, conv_w, conv_b,
                                                  BcatT_hi, BcatT_lo, b_dt, xc, dtb, bc);
    scan_a_k   <<<dim3(BSZ * NCHUNK), 256, 0, stream>>>(dtb, xc, bc, A_log, sumdt, Fst);
    scan_b_k   <<<dim3(BSZ * DI * DS / 256), 256, 0, stream>>>(sumdt, A_log, Fst);
    scan_c_k   <<<dim3(BSZ * NCHUNK), 256, 0, stream>>>(dtb, xc, bc, xz, A_log, Dw, Fst, yb);
    gemm_out_k <<<dim3(4, 64, BSZ), 256, 0, stream>>>(yb, WoutT_hi, WoutT_lo, out);
}

// Round 9
// 171.770 us; speedup vs baseline: 1.1445x; 1.1445x over previous
//
#include <hip/hip_runtime.h>
#include <math.h>

#define BSZ 2
#define LSEQ 4096
#define DM 256      // d_model
#define DI 256      // d_inner
#define DS 16       // d_state
#define DR 16       // dt_rank
#define NIN 512     // 2*DI
#define NCHUNK 256
#define LCHUNK 16
#define NB2 320     // padded Bcat width (288 real: 256 dt + 32 bc)

typedef __attribute__((ext_vector_type(8))) short short8;
typedef __attribute__((ext_vector_type(4))) float floatx4;

__device__ __forceinline__ float sigmoid_f(float v) {
    return __builtin_amdgcn_rcpf(1.0f + __expf(-v));
}

__device__ __forceinline__ unsigned int bf16_rne(float v) {
    unsigned int u = __float_as_uint(v);
    return (u + 0x7FFFu + ((u >> 16) & 1u)) >> 16;
}

// ---------------- setup: split W_in/W_out transposed + build BcatT ----------------
__global__ __launch_bounds__(512) void setup_k(const float* __restrict__ W_in,
                                               const float* __restrict__ W_out,
                                               const float* __restrict__ W_x,
                                               const float* __restrict__ W_dt,
                                               unsigned short* __restrict__ WinT_hi,
                                               unsigned short* __restrict__ WinT_lo,
                                               unsigned short* __restrict__ WoutT_hi,
                                               unsigned short* __restrict__ WoutT_lo,
                                               unsigned short* __restrict__ BcatT_hi,
                                               unsigned short* __restrict__ BcatT_lo) {
    __shared__ float wr[16];
    const int k = blockIdx.x;          // 0..255
    const int t = threadIdx.x;         // 0..511
    if (t < 16) wr[t] = W_x[(size_t)k * 48 + t];
    {
        float v = W_in[(size_t)k * NIN + t];
        unsigned int h = bf16_rne(v);
        float r = v - __uint_as_float(h << 16);
        WinT_hi[(size_t)t * DM + k] = (unsigned short)h;
        WinT_lo[(size_t)t * DM + k] = (unsigned short)bf16_rne(r);
    }
    if (t < DM) {
        float v = W_out[(size_t)k * DM + t];
        unsigned int h = bf16_rne(v);
        float r = v - __uint_as_float(h << 16);
        WoutT_hi[(size_t)t * DM + k] = (unsigned short)h;
        WoutT_lo[(size_t)t * DM + k] = (unsigned short)bf16_rne(r);
    }
    __syncthreads();
    if (t < NB2) {
        float v;
        if (t < 256) {
            float acc = 0.f;
#pragma unroll
            for (int r = 0; r < 16; ++r) acc = fmaf(wr[r], W_dt[r * DI + t], acc);
            v = acc;
        } else if (t < 288) {
            v = W_x[(size_t)k * 48 + 16 + (t - 256)];
        } else {
            v = 0.f;
        }
        unsigned int h = bf16_rne(v);
        float r = v - __uint_as_float(h << 16);
        BcatT_hi[(size_t)t * DM + k] = (unsigned short)h;
        BcatT_lo[(size_t)t * DM + k] = (unsigned short)bf16_rne(r);
    }
}

// ---------------- gemm_in (MFMA bf16x3): xz = x^T @ W_in; z-half gets SiLU in epilogue ----------------
__global__ __launch_bounds__(256) void gemm_in_k(const float* __restrict__ x,
                                                 const unsigned short* __restrict__ WT_hi,
                                                 const unsigned short* __restrict__ WT_lo,
                                                 float* __restrict__ xz) {
    __shared__ unsigned short sA[128][40];
    __shared__ unsigned short sB[128][40];
    const int b  = blockIdx.z;
    const int m0 = blockIdx.y * 64;
    const int n0 = blockIdx.x * 64;
    const int t  = threadIdx.x;
    const int w    = t >> 6;
    const int lane = t & 63;
    const int kp = t & 15;
    const int g  = t >> 4;

    const int mwb = (w & 1) * 32;
    const int nwb = (w >> 1) * 32;
    const int fr  = lane & 15;
    const int q   = lane >> 4;

    const int brow = t >> 2;
    const int bkq8 = (t & 3) * 8;

    floatx4 acc[2][2];
#pragma unroll
    for (int mi = 0; mi < 2; ++mi)
#pragma unroll
        for (int ni = 0; ni < 2; ++ni) acc[mi][ni] = (floatx4){0.f, 0.f, 0.f, 0.f};

    for (int k0 = 0; k0 < DM; k0 += 32) {
        {
            const float* pa = x + ((size_t)b * DM + k0 + 2 * kp) * LSEQ + m0 + 4 * g;
            float4 fa0 = *(const float4*)(pa);
            float4 fa1 = *(const float4*)(pa + LSEQ);
            const float* a0 = (const float*)&fa0;
            const float* a1 = (const float*)&fa1;
#pragma unroll
            for (int j = 0; j < 4; ++j) {
                int m = 4 * g + j;
                unsigned int h0 = bf16_rne(a0[j]);
                unsigned int h1 = bf16_rne(a1[j]);
                float r0 = a0[j] - __uint_as_float(h0 << 16);
                float r1 = a1[j] - __uint_as_float(h1 << 16);
                unsigned int l0 = bf16_rne(r0);
                unsigned int l1 = bf16_rne(r1);
                *(unsigned int*)&sA[m][2 * kp]      = h0 | (h1 << 16);
                *(unsigned int*)&sA[64 + m][2 * kp] = l0 | (l1 << 16);
            }
            const size_t boff = (size_t)(n0 + brow) * DM + k0 + bkq8;
            *(short8*)&sB[brow][bkq8]      = *(const short8*)(WT_hi + boff);
            *(short8*)&sB[64 + brow][bkq8] = *(const short8*)(WT_lo + boff);
        }
        __syncthreads();

        short8 ah[2], al[2], bh[2], bl[2];
#pragma unroll
        for (int mi = 0; mi < 2; ++mi) {
            int mr = mwb + mi * 16 + fr;
            ah[mi] = *(const short8*)&sA[mr][q * 8];
            al[mi] = *(const short8*)&sA[64 + mr][q * 8];
        }
#pragma unroll
        for (int ni = 0; ni < 2; ++ni) {
            int nr = nwb + ni * 16 + fr;
            bh[ni] = *(const short8*)&sB[nr][q * 8];
            bl[ni] = *(const short8*)&sB[64 + nr][q * 8];
        }
#pragma unroll
        for (int mi = 0; mi < 2; ++mi)
#pragma unroll
            for (int ni = 0; ni < 2; ++ni) {
                acc[mi][ni] = __builtin_amdgcn_mfma_f32_16x16x32_bf16(ah[mi], bh[ni], acc[mi][ni], 0, 0, 0);
                acc[mi][ni] = __builtin_amdgcn_mfma_f32_16x16x32_bf16(ah[mi], bl[ni], acc[mi][ni], 0, 0, 0);
                acc[mi][ni] = __builtin_amdgcn_mfma_f32_16x16x32_bf16(al[mi], bh[ni], acc[mi][ni], 0, 0, 0);
            }
        __syncthreads();
    }

    const bool isz = (n0 >= 256);   // z-half: store silu(z)
#pragma unroll
    for (int mi = 0; mi < 2; ++mi)
#pragma unroll
        for (int ni = 0; ni < 2; ++ni) {
#pragma unroll
            for (int r = 0; r < 4; ++r) {
                int m = m0 + mwb + mi * 16 + q * 4 + r;
                int n = n0 + nwb + ni * 16 + fr;
                float v = acc[mi][ni][r];
                if (isz) v = v * sigmoid_f(v);
                xz[((size_t)b * LSEQ + m) * NIN + n] = v;
            }
        }
}

// ---------------- conv + silu (standalone, coalesced): xc[b,l,d] ----------------
__global__ __launch_bounds__(256) void conv_silu_k(const float* __restrict__ xz,
                                                   const float* __restrict__ conv_w,
                                                   const float* __restrict__ conv_b,
                                                   float* __restrict__ xc) {
    const int t   = threadIdx.x;
    const int idx = blockIdx.x * 4 + (t >> 6);
    const int b   = idx >> 12;
    const int l   = idx & (LSEQ - 1);
    const int dq  = (t & 63) << 2;

    float4 cw0 = *(const float4*)(conv_w + (dq + 0) * 4);
    float4 cw1 = *(const float4*)(conv_w + (dq + 1) * 4);
    float4 cw2 = *(const float4*)(conv_w + (dq + 2) * 4);
    float4 cw3 = *(const float4*)(conv_w + (dq + 3) * 4);
    const float* cwp0 = (const float*)&cw0;
    const float* cwp1 = (const float*)&cw1;
    const float* cwp2 = (const float*)&cw2;
    const float* cwp3 = (const float*)&cw3;

    float4 acc = *(const float4*)(conv_b + dq);
#pragma unroll
    for (int k = 0; k < 4; ++k) {
        int ls = l - 3 + k;
        if (ls >= 0) {
            float4 v = *(const float4*)(xz + ((size_t)b * LSEQ + ls) * NIN + dq);
            acc.x = fmaf(v.x, cwp0[k], acc.x);
            acc.y = fmaf(v.y, cwp1[k], acc.y);
            acc.z = fmaf(v.z, cwp2[k], acc.z);
            acc.w = fmaf(v.w, cwp3[k], acc.w);
        }
    }
    acc.x *= sigmoid_f(acc.x);
    acc.y *= sigmoid_f(acc.y);
    acc.z *= sigmoid_f(acc.z);
    acc.w *= sigmoid_f(acc.w);
    *(float4*)(xc + (size_t)idx * DI + dq) = acc;
}

// ---------------- gemm_x2 (MFMA bf16x3): [dt | bc] = xc @ Bcat ----------------
__global__ __launch_bounds__(256) void gemm_x2_k(const float* __restrict__ xc,
                                                 const unsigned short* __restrict__ BT_hi,
                                                 const unsigned short* __restrict__ BT_lo,
                                                 const float* __restrict__ b_dt,
                                                 float* __restrict__ dt,
                                                 float* __restrict__ bc) {
    __shared__ unsigned short sA[128][40];
    __shared__ unsigned short sB[128][40];
    const int m0 = blockIdx.y * 64;
    const int n0 = blockIdx.x * 64;
    const int t  = threadIdx.x;
    const int w    = t >> 6;
    const int lane = t & 63;
    const int mwb = (w & 1) * 32;
    const int nwb = (w >> 1) * 32;
    const int fr  = lane & 15;
    const int q   = lane >> 4;

    const int row = t >> 2;
    const int kq8 = (t & 3) * 8;

    floatx4 acc[2][2];
#pragma unroll
    for (int mi = 0; mi < 2; ++mi)
#pragma unroll
        for (int ni = 0; ni < 2; ++ni) acc[mi][ni] = (floatx4){0.f, 0.f, 0.f, 0.f};

    for (int k0 = 0; k0 < DI; k0 += 32) {
        {
            const float* pa = xc + (size_t)(m0 + row) * DI + k0 + kq8;
            float v[8];
            *(float4*)(v)     = *(const float4*)(pa);
            *(float4*)(v + 4) = *(const float4*)(pa + 4);
            short8 hi, lo;
#pragma unroll
            for (int j = 0; j < 8; ++j) {
                unsigned int h = bf16_rne(v[j]);
                float r = v[j] - __uint_as_float(h << 16);
                hi[j] = (short)h;
                lo[j] = (short)bf16_rne(r);
            }
            *(short8*)&sA[row][kq8]      = hi;
            *(short8*)&sA[64 + row][kq8] = lo;

            const size_t boff = (size_t)(n0 + row) * DM + k0 + kq8;
            *(short8*)&sB[row][kq8]      = *(const short8*)(BT_hi + boff);
            *(short8*)&sB[64 + row][kq8] = *(const short8*)(BT_lo + boff);
        }
        __syncthreads();

        short8 ah[2], al[2], bh[2], bl[2];
#pragma unroll
        for (int mi = 0; mi < 2; ++mi) {
            int mr = mwb + mi * 16 + fr;
            ah[mi] = *(const short8*)&sA[mr][q * 8];
            al[mi] = *(const short8*)&sA[64 + mr][q * 8];
        }
#pragma unroll
        for (int ni = 0; ni < 2; ++ni) {
            int nr = nwb + ni * 16 + fr;
            bh[ni] = *(const short8*)&sB[nr][q * 8];
            bl[ni] = *(const short8*)&sB[64 + nr][q * 8];
        }
#pragma unroll
        for (int mi = 0; mi < 2; ++mi)
#pragma unroll
            for (int ni = 0; ni < 2; ++ni) {
                acc[mi][ni] = __builtin_amdgcn_mfma_f32_16x16x32_bf16(ah[mi], bh[ni], acc[mi][ni], 0, 0, 0);
                acc[mi][ni] = __builtin_amdgcn_mfma_f32_16x16x32_bf16(ah[mi], bl[ni], acc[mi][ni], 0, 0, 0);
                acc[mi][ni] = __builtin_amdgcn_mfma_f32_16x16x32_bf16(al[mi], bh[ni], acc[mi][ni], 0, 0, 0);
            }
        __syncthreads();
    }

#pragma unroll
    for (int mi = 0; mi < 2; ++mi)
#pragma unroll
        for (int ni = 0; ni < 2; ++ni) {
            int n = n0 + nwb + ni * 16 + fr;
            if (n < 256) {
                float bd = b_dt[n];
#pragma unroll
                for (int r = 0; r < 4; ++r) {
                    int m = m0 + mwb + mi * 16 + q * 4 + r;
                    float a2 = acc[mi][ni][r] + bd;
                    float sp = fmaxf(a2, 0.f) + __logf(1.f + __expf(-fabsf(a2)));
                    dt[(size_t)m * DI + n] = sp;
                }
            } else if (n < 288) {
#pragma unroll
                for (int r = 0; r < 4; ++r) {
                    int m = m0 + mwb + mi * 16 + q * 4 + r;
                    bc[(size_t)m * 32 + (n - 256)] = acc[mi][ni][r];
                }
            }
        }
}

// ---------------- scan phase A: local final F + per-chunk dt-sum ----------------
__global__ __launch_bounds__(256) void scan_a_k(const float* __restrict__ dt,
                                                const float* __restrict__ xc,
                                                const float* __restrict__ bc,
                                                const float* __restrict__ A_log,
                                                float* __restrict__ sumdt,
                                                float* __restrict__ Fst) {
    __shared__ float Bl[LCHUNK][16];
    const int blk   = blockIdx.x;
    const int b     = blk / NCHUNK;
    const int chunk = blk % NCHUNK;
    const int d     = threadIdx.x;
    const int l0    = chunk * LCHUNK;

    if (d < LCHUNK * 4) {
        int l = d >> 2, q = d & 3;
        *(float4*)(&Bl[l][q * 4]) =
            *(const float4*)(bc + (size_t)(b * LSEQ + l0 + l) * 32 + q * 4);
    }
    float Ads[16];
#pragma unroll
    for (int s = 0; s < 16; ++s) Ads[s] = -expf(A_log[d * DS + s]);
    __syncthreads();

    float h[16];
#pragma unroll
    for (int s = 0; s < 16; ++s) h[s] = 0.f;
    float sd = 0.f;

    const float* dtp = dt + ((size_t)b * LSEQ + l0) * DI + d;
    const float* xcp = xc + ((size_t)b * LSEQ + l0) * DI + d;

#pragma unroll 4
    for (int i = 0; i < LCHUNK; ++i) {
        float dtv = dtp[(size_t)i * DI];
        float xcv = xcp[(size_t)i * DI];
        float du  = dtv * xcv;
        sd += dtv;
        float4 b0 = *(float4*)(&Bl[i][0]);
        float4 b1 = *(float4*)(&Bl[i][4]);
        float4 b2 = *(float4*)(&Bl[i][8]);
        float4 b3 = *(float4*)(&Bl[i][12]);
        float bv[16] = {b0.x,b0.y,b0.z,b0.w, b1.x,b1.y,b1.z,b1.w,
                        b2.x,b2.y,b2.z,b2.w, b3.x,b3.y,b3.z,b3.w};
#pragma unroll
        for (int s = 0; s < 16; ++s) {
            float a = __expf(dtv * Ads[s]);
            h[s] = fmaf(h[s], a, du * bv[s]);
        }
    }
    size_t base = ((size_t)(b * DI + d) * NCHUNK + chunk) * DS;
#pragma unroll
    for (int q = 0; q < 4; ++q)
        *(float4*)(Fst + base + q * 4) = make_float4(h[q*4], h[q*4+1], h[q*4+2], h[q*4+3]);
    sumdt[(size_t)(b * DI + d) * NCHUNK + chunk] = sd;
}

// ---------------- scan phase B: chunk-prefix; P reconstructed from sumdt ----------------
__global__ __launch_bounds__(256) void scan_b_k(const float* __restrict__ sumdt,
                                                const float* __restrict__ A_log,
                                                float* __restrict__ Fst) {
    const int t = blockIdx.x * 256 + threadIdx.x;
    const int s = t & 15;
    const int d = (t >> 4) & (DI - 1);
    const int b = t >> 12;
    const float Ads = -expf(A_log[d * DS + s]);
    size_t base = ((size_t)(b * DI + d) * NCHUNK) * DS + s;
    const float* sdp = sumdt + (size_t)(b * DI + d) * NCHUNK;
    float st = 0.f;
#pragma unroll 8
    for (int c = 0; c < NCHUNK; ++c) {
        size_t idx = base + (size_t)c * DS;
        float P = __expf(sdp[c] * Ads);
        float F = Fst[idx];
        Fst[idx] = st;
        st = fmaf(P, st, F);
    }
}

// ---------------- scan phase C ----------------
__global__ __launch_bounds__(256) void scan_c_k(const float* __restrict__ dt,
                                                const float* __restrict__ xc,
                                                const float* __restrict__ bc,
                                                const float* __restrict__ xz,
                                                const float* __restrict__ A_log,
                                                const float* __restrict__ Dw,
                                                const float* __restrict__ carry,
                                                float* __restrict__ y) {
    __shared__ float BC[LCHUNK][32];
    const int blk   = blockIdx.x;
    const int b     = blk / NCHUNK;
    const int chunk = blk % NCHUNK;
    const int d     = threadIdx.x;
    const int l0    = chunk * LCHUNK;

    if (d < LCHUNK * 8) {
        int l = d >> 3, q = d & 7;
        *(float4*)(&BC[l][q * 4]) =
            *(const float4*)(bc + (size_t)(b * LSEQ + l0 + l) * 32 + q * 4);
    }
    float Ads[16];
#pragma unroll
    for (int s = 0; s < 16; ++s) Ads[s] = -expf(A_log[d * DS + s]);
    const float Dd = Dw[d];

    float h[16];
    size_t cbase = ((size_t)(b * DI + d) * NCHUNK + chunk) * DS;
#pragma unroll
    for (int q = 0; q < 4; ++q) {
        float4 c4 = *(const float4*)(carry + cbase + q * 4);
        h[q*4] = c4.x; h[q*4+1] = c4.y; h[q*4+2] = c4.z; h[q*4+3] = c4.w;
    }
    __syncthreads();

    const float* dtp = dt + ((size_t)b * LSEQ + l0) * DI + d;
    const float* xcp = xc + ((size_t)b * LSEQ + l0) * DI + d;
    const float* zp  = xz + ((size_t)b * LSEQ + l0) * NIN + DI + d;   // already silu'd
    float* yout      = y  + ((size_t)b * LSEQ + l0) * DI + d;

#pragma unroll 4
    for (int i = 0; i < LCHUNK; ++i) {
        float dtv = dtp[(size_t)i * DI];
        float xcv = xcp[(size_t)i * DI];
        float zs  = zp[(size_t)i * NIN];
        float du  = dtv * xcv;
        float4 b0 = *(float4*)(&BC[i][0]);
        float4 b1 = *(float4*)(&BC[i][4]);
        float4 b2 = *(float4*)(&BC[i][8]);
        float4 b3 = *(float4*)(&BC[i][12]);
        float4 c0 = *(float4*)(&BC[i][16]);
        float4 c1 = *(float4*)(&BC[i][20]);
        float4 c2 = *(float4*)(&BC[i][24]);
        float4 c3 = *(float4*)(&BC[i][28]);
        float bv[16] = {b0.x,b0.y,b0.z,b0.w, b1.x,b1.y,b1.z,b1.w,
                        b2.x,b2.y,b2.z,b2.w, b3.x,b3.y,b3.z,b3.w};
        float cv[16] = {c0.x,c0.y,c0.z,c0.w, c1.x,c1.y,c1.z,c1.w,
                        c2.x,c2.y,c2.z,c2.w, c3.x,c3.y,c3.z,c3.w};
        float yv = 0.f;
#pragma unroll
        for (int s = 0; s < 16; ++s) {
            float a = __expf(dtv * Ads[s]);
            h[s] = fmaf(h[s], a, du * bv[s]);
            yv = fmaf(h[s], cv[s], yv);
        }
        float yf = fmaf(xcv, Dd, yv);
        yout[(size_t)i * DI] = yf * zs;
    }
}

// ---------------- gemm_out (MFMA bf16x3): out[b,c,l] = sum_d y[b,l,d] * W_out[d,c] ----------------
__global__ __launch_bounds__(256) void gemm_out_k(const float* __restrict__ y,
                                                  const unsigned short* __restrict__ WT_hi,
                                                  const unsigned short* __restrict__ WT_lo,
                                                  float* __restrict__ out) {
    __shared__ unsigned short sA[128][40];
    __shared__ unsigned short sB[128][40];
    const int b  = blockIdx.z;
    const int m0 = blockIdx.y * 64;    // l
    const int n0 = blockIdx.x * 64;    // c
    const int t  = threadIdx.x;
    const int w    = t >> 6;
    const int lane = t & 63;
    const int mwb = (w & 1) * 32;
    const int nwb = (w >> 1) * 32;
    const int fr  = lane & 15;
    const int q   = lane >> 4;

    const int row = t >> 2;
    const int kq8 = (t & 3) * 8;

    floatx4 acc[2][2];
#pragma unroll
    for (int mi = 0; mi < 2; ++mi)
#pragma unroll
        for (int ni = 0; ni < 2; ++ni) acc[mi][ni] = (floatx4){0.f, 0.f, 0.f, 0.f};

    for (int k0 = 0; k0 < DI; k0 += 32) {
        {
            const float* pa = y + ((size_t)b * LSEQ + m0 + row) * DI + k0 + kq8;
            float v[8];
            *(float4*)(v)     = *(const float4*)(pa);
            *(float4*)(v + 4) = *(const float4*)(pa + 4);
            short8 hi, lo;
#pragma unroll
            for (int j = 0; j < 8; ++j) {
                unsigned int h = bf16_rne(v[j]);
                float r = v[j] - __uint_as_float(h << 16);
                hi[j] = (short)h;
                lo[j] = (short)bf16_rne(r);
            }
            *(short8*)&sA[row][kq8]      = hi;
            *(short8*)&sA[64 + row][kq8] = lo;

            const size_t boff = (size_t)(n0 + row) * DM + k0 + kq8;
            *(short8*)&sB[row][kq8]      = *(const short8*)(WT_hi + boff);
            *(short8*)&sB[64 + row][kq8] = *(const short8*)(WT_lo + boff);
        }
        __syncthreads();

        short8 ah[2], al[2], bh[2], bl[2];
#pragma unroll
        for (int mi = 0; mi < 2; ++mi) {
            int mr = mwb + mi * 16 + fr;
            ah[mi] = *(const short8*)&sA[mr][q * 8];
            al[mi] = *(const short8*)&sA[64 + mr][q * 8];
        }
#pragma unroll
        for (int ni = 0; ni < 2; ++ni) {
            int nr = nwb + ni * 16 + fr;
            bh[ni] = *(const short8*)&sB[nr][q * 8];
            bl[ni] = *(const short8*)&sB[64 + nr][q * 8];
        }
#pragma unroll
        for (int mi = 0; mi < 2; ++mi)
#pragma unroll
            for (int ni = 0; ni < 2; ++ni) {
                acc[mi][ni] = __builtin_amdgcn_mfma_f32_16x16x32_bf16(ah[mi], bh[ni], acc[mi][ni], 0, 0, 0);
                acc[mi][ni] = __builtin_amdgcn_mfma_f32_16x16x32_bf16(ah[mi], bl[ni], acc[mi][ni], 0, 0, 0);
                acc[mi][ni] = __builtin_amdgcn_mfma_f32_16x16x32_bf16(al[mi], bh[ni], acc[mi][ni], 0, 0, 0);
            }
        __syncthreads();
    }

#pragma unroll
    for (int mi = 0; mi < 2; ++mi)
#pragma unroll
        for (int ni = 0; ni < 2; ++ni) {
            int c = n0 + nwb + ni * 16 + fr;
            float* op = out + ((size_t)b * DM + c) * LSEQ + m0 + mwb + mi * 16 + q * 4;
            *(float4*)op = make_float4(acc[mi][ni][0], acc[mi][ni][1],
                                       acc[mi][ni][2], acc[mi][ni][3]);
        }
}

extern "C" void kernel_launch(void* const* d_in, const int* in_sizes, int n_in,
                              void* d_out, int out_size, void* d_ws, size_t ws_size,
                              hipStream_t stream) {
    const float* x      = (const float*)d_in[0];
    const float* W_in   = (const float*)d_in[1];
    const float* conv_w = (const float*)d_in[2];
    const float* conv_b = (const float*)d_in[3];
    const float* W_x    = (const float*)d_in[4];
    const float* W_dt   = (const float*)d_in[5];
    const float* b_dt   = (const float*)d_in[6];
    const float* A_log  = (const float*)d_in[7];
    const float* Dw     = (const float*)d_in[8];
    const float* W_out  = (const float*)d_in[9];
    float* out = (float*)d_out;

    float* ws    = (float*)d_ws;
    float* xz    = ws;                    // B*L*512            = 4,194,304
    float* xc    = xz + 4194304;          // B*L*256            = 2,097,152
    float* bc    = xc + 2097152;          // B*L*32             =   262,144
    float* dtb   = bc + 262144;           // B*L*256            = 2,097,152
    float* sumdt = dtb + 2097152;         // B*DI*NCHUNK        =   131,072
    float* Fst   = sumdt + 131072;        // B*DI*NCHUNK*DS     = 2,097,152
    float* yb    = Fst + 2097152;         // B*L*DI             = 2,097,152
    unsigned short* WinT_hi  = (unsigned short*)(yb + 2097152);   // 512*256
    unsigned short* WinT_lo  = WinT_hi + 131072;
    unsigned short* WoutT_hi = WinT_lo + 131072;                  // 256*256
    unsigned short* WoutT_lo = WoutT_hi + 65536;
    unsigned short* BcatT_hi = WoutT_lo + 65536;                  // 320*256
    unsigned short* BcatT_lo = BcatT_hi + 81920;

    setup_k    <<<dim3(256), 512, 0, stream>>>(W_in, W_out, W_x, W_dt,
                                               WinT_hi, WinT_lo, WoutT_hi, WoutT_lo,
                                               BcatT_hi, BcatT_lo);
    gemm_in_k  <<<dim3(8, 64, BSZ), 256, 0, stream>>>(x, WinT_hi, WinT_lo, xz);
    conv_silu_k<<<dim3(BSZ * LSEQ / 4), 256, 0, stream>>>(xz, conv_w, conv_b, xc);
    gemm_x2_k  <<<dim3(5, 128), 256, 0, stream>>>(xc, BcatT_hi, BcatT_lo, b_dt, dtb, bc);
    scan_a_k   <<<dim3(BSZ * NCHUNK), 256, 0, stream>>>(dtb, xc, bc, A_log, sumdt, Fst);
    scan_b_k   <<<dim3(BSZ * DI * DS / 256), 256, 0, stream>>>(sumdt, A_log, Fst);
    scan_c_k   <<<dim3(BSZ * NCHUNK), 256, 0, stream>>>(dtb, xc, bc, xz, A_log, Dw, Fst, yb);
    gemm_out_k <<<dim3(4, 64, BSZ), 256, 0, stream>>>(yb, WoutT_hi, WoutT_lo, out);
}